// Round 13
// baseline (187.836 us; speedup 1.0000x reference)
//
#include <hip/hip_runtime.h>
#include <hip/hip_bf16.h>

#define NH 12
#define SEQ 4096
#define E 768
#define DK 64

typedef float f32x4 __attribute__((ext_vector_type(4)));
typedef float f32x16 __attribute__((ext_vector_type(16)));
typedef __bf16 bf16x8 __attribute__((ext_vector_type(8)));
typedef __bf16 bf16x4 __attribute__((ext_vector_type(4)));
typedef unsigned u32x2 __attribute__((ext_vector_type(2)));
typedef unsigned u32x4 __attribute__((ext_vector_type(4)));

#define MFMA16(a, b, c) __builtin_amdgcn_mfma_f32_16x16x32_bf16((a), (b), (c), 0, 0, 0)
#define MFMA32(a, b, c) __builtin_amdgcn_mfma_f32_32x32x16_bf16((a), (b), (c), 0, 0, 0)

// log2(e) / sqrt(dk); folded into K weights at wsplit time.
#define SCL 0.18033688011112042f
// defer-max threshold in log2 units: P bounded by 2^10.8
#define DEFER 10.8f

// Tasks per head: windows 0..127, window w has k=(w>>1)+1 tiles, ceil(k/16)
// splits -> 32*1 + 32*2 + 32*3 + 32*4 = 320 tasks/head, 3840 total.
#define TPH 320
#define NTASK 3840
#define PART_SZ 4352  // 2*16*64 bf16 (4096B) + m[32],l[32] f32 (256B)

__device__ __forceinline__ void gload16(const void* g, void* l) {
    __builtin_amdgcn_global_load_lds(
        (const __attribute__((address_space(1))) void*)g,
        (__attribute__((address_space(3))) void*)l, 16, 0, 0);
}

__device__ __forceinline__ void block_sync() {
    __builtin_amdgcn_sched_barrier(0);
    __builtin_amdgcn_s_barrier();
    __builtin_amdgcn_sched_barrier(0);
}

__device__ __forceinline__ unsigned cvtpk(float lo, float hi) {
    unsigned r;
    asm("v_cvt_pk_bf16_f32 %0, %1, %2" : "=v"(r) : "v"(lo), "v"(hi));
    return r;
}
__device__ __forceinline__ u32x2 plswap(unsigned a, unsigned b) {
    return __builtin_amdgcn_permlane32_swap(a, b, false, false);
}
__device__ __forceinline__ float xhalf_max(float v) {
    u32x2 r = plswap(__float_as_uint(v), __float_as_uint(v));
    return fmaxf(__uint_as_float(r.x), __uint_as_float(r.y));
}
__device__ __forceinline__ float xhalf_add(float v) {
    u32x2 r = plswap(__float_as_uint(v), __float_as_uint(v));
    return __uint_as_float(r.x) + __uint_as_float(r.y);
}

// ---------------------------------------------------------------------------
// Kernel 0: split x into bf16 hi/lo
// ---------------------------------------------------------------------------
__global__ __launch_bounds__(256) void xsplit_kernel(const float* __restrict__ x,
                                                     __bf16* __restrict__ xh,
                                                     __bf16* __restrict__ xl) {
    int i = blockIdx.x * blockDim.x + threadIdx.x;
    float4 v = ((const float4*)x)[i];
    bf16x4 h, l;
    float vv[4] = {v.x, v.y, v.z, v.w};
#pragma unroll
    for (int j = 0; j < 4; ++j) {
        __bf16 hh = (__bf16)vv[j];
        h[j] = hh;
        l[j] = (__bf16)(vv[j] - (float)hh);
    }
    ((bf16x4*)xh)[i] = h;
    ((bf16x4*)xl)[i] = l;
}

// ---------------------------------------------------------------------------
// Kernel 1: split projection weights (hi/lo), transpose to [h][n][k].
// K weights pre-scaled by SCL so attention scores come out in log2 units.
// ---------------------------------------------------------------------------
__global__ void wsplit_kernel(const float* __restrict__ qp,
                              const float* __restrict__ kp,
                              const float* __restrict__ vp,
                              __bf16* __restrict__ wtq_h, __bf16* __restrict__ wtq_l,
                              __bf16* __restrict__ wtk_h, __bf16* __restrict__ wtk_l,
                              __bf16* __restrict__ wtv_h) {
    int idx = blockIdx.x * blockDim.x + threadIdx.x;
    if (idx >= NH * E * DK) return;
    int h = idx / (E * DK);
    int rem = idx - h * E * DK;
    int k = rem / DK;
    int n = rem - k * DK;
    int o = h * DK * E + n * E + k;  // [h][n][k]
    float q = qp[idx];
    __bf16 qh = (__bf16)q;
    wtq_h[o] = qh;
    wtq_l[o] = (__bf16)(q - (float)qh);
    float kk = kp[idx] * SCL;
    __bf16 kh = (__bf16)kk;
    wtk_h[o] = kh;
    wtk_l[o] = (__bf16)(kk - (float)kh);
    wtv_h[o] = (__bf16)vp[idx];
}

// ---------------------------------------------------------------------------
// Kernel 2a: fused Q+K projection. Block = 64 rows x 1 head, 4 waves x 16
// rows. Grid 768 = 3 blocks/CU. Q row-major; K FRAGMENT-LINEAR.
// ---------------------------------------------------------------------------
__global__ __launch_bounds__(256, 2) void proj_qk_kernel(
    const __bf16* __restrict__ xh, const __bf16* __restrict__ xl,
    const __bf16* __restrict__ wq_h_g, const __bf16* __restrict__ wq_l_g,
    const __bf16* __restrict__ wk_h_g, const __bf16* __restrict__ wk_l_g,
    __bf16* __restrict__ qh_o, __bf16* __restrict__ ql_o,
    __bf16* __restrict__ kh_o, __bf16* __restrict__ kl_o) {
    __shared__ char wlds[2][16384];  // [buf][ Wqh 4K | Wql 4K | Wkh 4K | Wkl 4K ]

    const int wg = (blockIdx.x & 7) * 96 + (blockIdx.x >> 3);  // 768 = 8 x 96
    const int head = wg >> 6;
    const int rb = wg & 63;
    const int wave = threadIdx.x >> 6;
    const int lane = threadIdx.x & 63;
    const int lrow = lane & 15;
    const int lk8 = (lane >> 4) * 8;
    const int g4 = (lane >> 4) * 4;
    const int rowbase = rb * 64 + wave * 16;

    const char* wq_h_b = (const char*)(wq_h_g + head * DK * E);
    const char* wq_l_b = (const char*)(wq_l_g + head * DK * E);
    const char* wk_h_b = (const char*)(wk_h_g + head * DK * E);
    const char* wk_l_b = (const char*)(wk_l_g + head * DK * E);
    const char* base = (wave == 0) ? wq_h_b : (wave == 1) ? wq_l_b
                      : (wave == 2) ? wk_h_b : wk_l_b;
    const int srow = lane >> 2;
    const int scol = (lane & 3) * 16;

    auto STAGE = [&](int buf, int ks) {
#pragma unroll
        for (int r = 0; r < 4; ++r) {
            const char* src = base + (size_t)(r * 16 + srow) * (E * 2) + ks * 64 + scol;
            gload16(src, wlds[buf] + (wave * 4 + r) * 1024 + lane * 16);
        }
    };

    f32x4 accq[4], acck[4];
#pragma unroll
    for (int f = 0; f < 4; ++f) {
        accq[f] = (f32x4){0.f, 0.f, 0.f, 0.f};
        acck[f] = (f32x4){0.f, 0.f, 0.f, 0.f};
    }

    bf16x8 ah, al, ahn, aln;
    auto LOADA = [&](int ks, bf16x8& h, bf16x8& l) {
        size_t xo = (size_t)(rowbase + lrow) * E + ks * 32 + lk8;
        h = *(const bf16x8*)(xh + xo);
        l = *(const bf16x8*)(xl + xo);
    };

    LOADA(0, ah, al);
    STAGE(0, 0);
    int buf = 0;
    for (int ks = 0; ks < 24; ++ks) {
        if (ks < 23) {
            LOADA(ks + 1, ahn, aln);
            STAGE(buf ^ 1, ks + 1);
            asm volatile("s_waitcnt vmcnt(6)" ::: "memory");
        } else {
            asm volatile("s_waitcnt vmcnt(0)" ::: "memory");
        }
        block_sync();
#pragma unroll
        for (int f = 0; f < 4; ++f) {
            int bo = (f * 16 + lrow) * 64 + lk8 * 2;
            bf16x8 bqh = *(const bf16x8*)(wlds[buf] + bo);
            bf16x8 bql = *(const bf16x8*)(wlds[buf] + 4096 + bo);
            bf16x8 bkh = *(const bf16x8*)(wlds[buf] + 8192 + bo);
            bf16x8 bkl = *(const bf16x8*)(wlds[buf] + 12288 + bo);
            accq[f] = MFMA16(ah, bqh, accq[f]);
            accq[f] = MFMA16(ah, bql, accq[f]);
            accq[f] = MFMA16(al, bqh, accq[f]);
            acck[f] = MFMA16(ah, bkh, acck[f]);
            acck[f] = MFMA16(ah, bkl, acck[f]);
            acck[f] = MFMA16(al, bkh, acck[f]);
        }
        block_sync();
        if (ks < 23) {
            ah = ahn;
            al = aln;
        }
        buf ^= 1;
    }

    char* khb = (char*)kh_o + (size_t)head * SEQ * DK * 2;
    char* klb = (char*)kl_o + (size_t)head * SEQ * DK * 2;
#pragma unroll
    for (int f = 0; f < 4; ++f)
#pragma unroll
        for (int r = 0; r < 4; ++r) {
            int srow_o = rowbase + g4 + r;
            int d = f * 16 + lrow;
            size_t o = (size_t)head * SEQ * DK + (size_t)srow_o * DK + d;
            float qv = accq[f][r];
            __bf16 qhh = (__bf16)qv;
            qh_o[o] = qhh;
            ql_o[o] = (__bf16)(qv - (float)qhh);
            size_t ko = (size_t)(srow_o >> 6) * 8192 + ((srow_o >> 5) & 1) * 4096
                      + (size_t)f * 1024
                      + ((srow_o & 31) + 32 * ((lrow >> 3) & 1)) * 16 + (lrow & 7) * 2;
            float kv = acck[f][r];
            __bf16 khh = (__bf16)kv;
            *(__bf16*)(khb + ko) = khh;
            *(__bf16*)(klb + ko) = (__bf16)(kv - (float)khh);
        }
}

// ---------------------------------------------------------------------------
// Kernel 2b: V projection (1-term, operand-swapped). Grid 768. FRAGMENT-LINEAR.
// ---------------------------------------------------------------------------
__global__ __launch_bounds__(256) void proj_v_kernel(
    const __bf16* __restrict__ xh, const __bf16* __restrict__ w_v,
    __bf16* __restrict__ vt_o) {
    __shared__ char wlds[2][4096];

    const int wg = (blockIdx.x & 7) * 96 + (blockIdx.x >> 3);
    const int head = wg >> 6;
    const int rb = wg & 63;
    const int wave = threadIdx.x >> 6;
    const int lane = threadIdx.x & 63;
    const int lrow = lane & 15;
    const int lk8 = (lane >> 4) * 8;
    const int g4 = (lane >> 4) * 4;
    const int rowbase = rb * 64 + wave * 16;

    const char* wv_b = (const char*)(w_v + head * DK * E);
    const int srow = lane >> 2;
    const int scol = (lane & 3) * 16;

    auto STAGE = [&](int buf, int ks) {
        const char* src = wv_b + (size_t)(wave * 16 + srow) * (E * 2) + ks * 64 + scol;
        gload16(src, wlds[buf] + wave * 1024 + lane * 16);
    };

    f32x4 acc[4];
#pragma unroll
    for (int f = 0; f < 4; ++f) acc[f] = (f32x4){0.f, 0.f, 0.f, 0.f};

    bf16x8 ah, ahn;
    auto LOADA = [&](int ks, bf16x8& h) {
        size_t xo = (size_t)(rowbase + lrow) * E + ks * 32 + lk8;
        h = *(const bf16x8*)(xh + xo);
    };

    LOADA(0, ah);
    STAGE(0, 0);
    int buf = 0;
    for (int ks = 0; ks < 24; ++ks) {
        if (ks < 23) {
            LOADA(ks + 1, ahn);
            STAGE(buf ^ 1, ks + 1);
            asm volatile("s_waitcnt vmcnt(2)" ::: "memory");
        } else {
            asm volatile("s_waitcnt vmcnt(0)" ::: "memory");
        }
        block_sync();
#pragma unroll
        for (int f = 0; f < 4; ++f) {
            int bo = (f * 16 + lrow) * 64 + lk8 * 2;
            bf16x8 bv = *(const bf16x8*)(wlds[buf] + bo);
            acc[f] = MFMA16(bv, ah, acc[f]);  // D[d][s]
        }
        block_sync();
        if (ks < 23) ah = ahn;
        buf ^= 1;
    }

    char* vb = (char*)vt_o + (size_t)head * DK * SEQ * 2;
#pragma unroll
    for (int f = 0; f < 4; ++f)
#pragma unroll
        for (int r = 0; r < 4; ++r) {
            int vd = f * 16 + g4 + r;
            int vs = rowbase + lrow;
            size_t vo = (size_t)(vs >> 6) * 8192 + ((vd >> 5) & 1) * 4096
                      + ((vs >> 4) & 3) * 1024
                      + ((vd & 31) + 32 * ((vs >> 3) & 1)) * 16 + (vs & 7) * 2;
            *(__bf16*)(vb + vo) = (__bf16)acc[f][r];
        }
}

// ---------------------------------------------------------------------------
// Kernel 3a: attention partials — EQUAL-WORK two-phase split-KV.
// 3840 tasks (head, window, split), each <=16 K-tiles, one independent wave
// per task, NO LDS, NO barriers -> flat occupancy, no decay tail (r12's
// 21% time-avg occupancy was work-imbalance decay). Partial (O' bf16 in
// register layout + m/l f32) written to workspace; phase 2 merges.
// ---------------------------------------------------------------------------
__global__ __launch_bounds__(256, 2) void attn_part_kernel(
    const __bf16* __restrict__ qh, const __bf16* __restrict__ ql,
    const __bf16* __restrict__ kh, const __bf16* __restrict__ kl,
    const __bf16* __restrict__ vt,
    char* __restrict__ part) {
    const int blk = (blockIdx.x & 7) * 120 + (blockIdx.x >> 3);  // 960 = 8 x 120
    const int wave = threadIdx.x >> 6;
    const int task = blk * 4 + wave;
    const int lane = threadIdx.x & 63;
    const int lq = lane & 31;
    const int lh = lane >> 5;

    const int head = task / TPH;
    const int t = task - head * TPH;
    int w, split, nsp;
    if (t < 32)       { w = t;                             split = 0;     nsp = 1; }
    else if (t < 96)  { int u = t - 32;  w = 32 + (u >> 1); split = u & 1; nsp = 2; }
    else if (t < 192) { int u = t - 96;  w = 64 + u / 3;    split = u % 3; nsp = 3; }
    else              { int u = t - 192; w = 96 + (u >> 2); split = u & 3; nsp = 4; }
    const int ktot = (w >> 1) + 1;           // window tile count
    const int lo = (split * ktot) / nsp;
    const int hi = ((split + 1) * ktot) / nsp;
    const int rowbase = w * 32;

    const size_t hoff = (size_t)head * SEQ * DK;

    // Q B-frags: lane holds Q[rowbase+lq][ds*16 + lh*8 + 0..7]
    bf16x8 qBh[4], qBl[4];
    {
        const __bf16* qph = qh + hoff + (size_t)(rowbase + lq) * DK + lh * 8;
        const __bf16* qpl = ql + hoff + (size_t)(rowbase + lq) * DK + lh * 8;
#pragma unroll
        for (int ds = 0; ds < 4; ++ds) {
            qBh[ds] = *(const bf16x8*)(qph + ds * 16);
            qBl[ds] = *(const bf16x8*)(qpl + ds * 16);
        }
    }

    // fragment-linear walking pointers (each load: +lane*16, 1KB coalesced)
    const char* kh_p = (const char*)(kh + hoff) + (size_t)lo * 8192 + lane * 16;
    const char* kl_p = (const char*)(kl + hoff) + (size_t)lo * 8192 + lane * 16;
    const char* vt_p = (const char*)(vt + (size_t)head * DK * SEQ) + (size_t)lo * 8192 + lane * 16;

    f32x16 O0 = (f32x16)0.0f, O1 = (f32x16)0.0f;
    float m = -3.0e38f, lsum = 0.f;

    for (int tt = lo; tt < hi; ++tt) {
        const int kb = tt * 64;

        // ---- S = K'^T Q (log2 units). s0: keys kb..kb+31, s1: +32..63 ----
        f32x16 s0 = (f32x16)0.0f, s1 = (f32x16)0.0f;
#pragma unroll
        for (int ds = 0; ds < 4; ++ds) {
            bf16x8 ah0 = *(const bf16x8*)(kh_p + ds * 1024);
            bf16x8 al0 = *(const bf16x8*)(kl_p + ds * 1024);
            bf16x8 ah1 = *(const bf16x8*)(kh_p + 4096 + ds * 1024);
            bf16x8 al1 = *(const bf16x8*)(kl_p + 4096 + ds * 1024);
            s0 = MFMA32(ah0, qBh[ds], s0);
            s1 = MFMA32(ah1, qBh[ds], s1);
            s0 = MFMA32(al0, qBh[ds], s0);
            s1 = MFMA32(al1, qBh[ds], s1);
            s0 = MFMA32(ah0, qBl[ds], s0);
            s1 = MFMA32(ah1, qBl[ds], s1);
        }

        // ---- V B-frags issued early: latency hides under the softmax ----
        bf16x8 v00 = *(const bf16x8*)(vt_p + 0);
        bf16x8 v01 = *(const bf16x8*)(vt_p + 1024);
        bf16x8 v10 = *(const bf16x8*)(vt_p + 2048);
        bf16x8 v11 = *(const bf16x8*)(vt_p + 3072);
        bf16x8 w00 = *(const bf16x8*)(vt_p + 4096);
        bf16x8 w01 = *(const bf16x8*)(vt_p + 5120);
        bf16x8 w10 = *(const bf16x8*)(vt_p + 6144);
        bf16x8 w11 = *(const bf16x8*)(vt_p + 7168);

        // ---- causal mask (only the window's last tile triggers) ----
        if (kb + 63 > rowbase) {
            int qa = rowbase + lq;
#pragma unroll
            for (int r = 0; r < 16; ++r) {
                int kp = kb + ((r & 3) + 8 * (r >> 2) + 4 * lh);
                if (kp > qa) s0[r] = -1.0e30f;
                if (kp + 32 > qa) s1[r] = -1.0e30f;
            }
        }

        // ---- row max: 4-chain tree + one cross-half swap ----
        float x0 = fmaxf(s0[0], s0[1]), x1 = fmaxf(s0[2], s0[3]);
        float x2 = fmaxf(s0[4], s0[5]), x3 = fmaxf(s0[6], s0[7]);
#pragma unroll
        for (int r = 8; r < 16; r += 4) {
            x0 = fmaxf(x0, fmaxf(s0[r], s0[r + 1]));
            x1 = fmaxf(x1, fmaxf(s0[r + 2], s0[r + 3]));
        }
#pragma unroll
        for (int r = 0; r < 16; r += 4) {
            x2 = fmaxf(x2, fmaxf(s1[r], s1[r + 1]));
            x3 = fmaxf(x3, fmaxf(s1[r + 2], s1[r + 3]));
        }
        float mx = xhalf_max(fmaxf(fmaxf(x0, x1), fmaxf(x2, x3)));

        // ---- defer-max rescale (rare); alpha broadcast via shfl ----
        if (!__all(mx - m <= DEFER)) {
            float mn = fmaxf(m, mx);
            float al = exp2f(m - mn);
            m = mn;
            lsum *= al;
#pragma unroll
            for (int r = 0; r < 16; ++r) {
                float a = __shfl(al, (r & 3) + 8 * (r >> 2) + 4 * lh);
                O0[r] *= a;
                O1[r] *= a;
            }
        }

        // ---- P = exp2(S - m); l accumulation ----
        s0 = s0 - m;
        s1 = s1 - m;
#pragma unroll
        for (int r = 0; r < 16; ++r) {
            s0[r] = exp2f(s0[r]);
            s1[r] = exp2f(s1[r]);
        }
        {
            f32x16 sv = s0 + s1;
            float p0 = 0.f, p1 = 0.f;
#pragma unroll
            for (int r = 0; r < 16; r += 4) {
                p0 += sv[r] + sv[r + 1];
                p1 += sv[r + 2] + sv[r + 3];
            }
            lsum += p0 + p1;
        }

        // ---- P -> PV A-frags: cvt_pk + permlane32_swap (in-register) ----
        unsigned W0 = cvtpk(s0[0], s0[1]), W1 = cvtpk(s0[2], s0[3]);
        unsigned W2 = cvtpk(s0[4], s0[5]), W3 = cvtpk(s0[6], s0[7]);
        unsigned W4 = cvtpk(s0[8], s0[9]), W5 = cvtpk(s0[10], s0[11]);
        unsigned W6 = cvtpk(s0[12], s0[13]), W7 = cvtpk(s0[14], s0[15]);
        u32x2 rA = plswap(W0, W2), rB = plswap(W1, W3);
        u32x2 rC = plswap(W4, W6), rD = plswap(W5, W7);
        bf16x8 p00 = __builtin_bit_cast(bf16x8, (u32x4){rA.x, rB.x, rA.y, rB.y});
        bf16x8 p01 = __builtin_bit_cast(bf16x8, (u32x4){rC.x, rD.x, rC.y, rD.y});
        W0 = cvtpk(s1[0], s1[1]); W1 = cvtpk(s1[2], s1[3]);
        W2 = cvtpk(s1[4], s1[5]); W3 = cvtpk(s1[6], s1[7]);
        W4 = cvtpk(s1[8], s1[9]); W5 = cvtpk(s1[10], s1[11]);
        W6 = cvtpk(s1[12], s1[13]); W7 = cvtpk(s1[14], s1[15]);
        rA = plswap(W0, W2); rB = plswap(W1, W3);
        rC = plswap(W4, W6); rD = plswap(W5, W7);
        bf16x8 p10 = __builtin_bit_cast(bf16x8, (u32x4){rA.x, rB.x, rA.y, rB.y});
        bf16x8 p11 = __builtin_bit_cast(bf16x8, (u32x4){rC.x, rD.x, rC.y, rD.y});

        // ---- O += P V ----
        O0 = MFMA32(p00, v00, O0);
        O0 = MFMA32(p01, v01, O0);
        O0 = MFMA32(p10, v10, O0);
        O0 = MFMA32(p11, v11, O0);
        O1 = MFMA32(p00, w00, O1);
        O1 = MFMA32(p01, w01, O1);
        O1 = MFMA32(p10, w10, O1);
        O1 = MFMA32(p11, w11, O1);

        kh_p += 8192;
        kl_p += 8192;
        vt_p += 8192;
    }

    // ---- write partial: O' bf16 pairs in register layout, m/l f32 ----
    char* pb = part + (size_t)task * PART_SZ;
    unsigned* ph = (unsigned*)pb;
#pragma unroll
    for (int r = 0; r < 16; r += 2) {
        ph[(r >> 1) * 64 + lane] = cvtpk(O0[r], O0[r + 1]);
        ph[512 + (r >> 1) * 64 + lane] = cvtpk(O1[r], O1[r + 1]);
    }
    float lf = xhalf_add(lsum);
    float* pm = (float*)(pb + 4096);
    if (lane < 32) {
        pm[lq] = m;
        pm[32 + lq] = lf;
    }
}

// ---------------------------------------------------------------------------
// Kernel 3b: combine partials — exact flash merge per (head, window).
// Grid 1536 blocks x 256 thr; thread handles (row, 8 d-elems).
// ---------------------------------------------------------------------------
__global__ __launch_bounds__(256) void attn_comb_kernel(
    const char* __restrict__ part, float* __restrict__ out) {
    const int W = blockIdx.x;  // 0..1535
    const int head = W >> 7, w = W & 127;
    int tb, nsp;
    if (w < 32)      { tb = w;                 nsp = 1; }
    else if (w < 64) { tb = 32 + (w - 32) * 2; nsp = 2; }
    else if (w < 96) { tb = 96 + (w - 64) * 3; nsp = 3; }
    else             { tb = 192 + (w - 96) * 4; nsp = 4; }
    tb += head * TPH;

    const int tid = threadIdx.x;
    const int row = tid >> 3;          // 0..31
    const int d0 = (tid & 7) * 8;      // 0..56
    const int lane0 = (d0 & 31) + 32 * ((row >> 2) & 1);
    const int r = (row & 3) + 4 * (row >> 3);
    const int word = (r >> 1) * 64;
    const int hi16 = r & 1;
    const char* p0 = part + (size_t)tb * PART_SZ;

    float mv[4], lv[4];
    float mstar = -3.0e38f;
    for (int s = 0; s < nsp; ++s) {
        const float* pm = (const float*)(p0 + s * PART_SZ + 4096);
        mv[s] = pm[row];
        lv[s] = pm[32 + row];
        mstar = fmaxf(mstar, mv[s]);
    }

    float acc[8] = {0.f, 0.f, 0.f, 0.f, 0.f, 0.f, 0.f, 0.f};
    float lt = 0.f;
    for (int s = 0; s < nsp; ++s) {
        float wgt = exp2f(mv[s] - mstar);
        lt += wgt * lv[s];
        const unsigned* pw = (const unsigned*)(p0 + s * PART_SZ + (d0 >> 5) * 2048);
        u32x4 a = *(const u32x4*)(pw + word + lane0);
        u32x4 b = *(const u32x4*)(pw + word + lane0 + 4);
#pragma unroll
        for (int j = 0; j < 8; ++j) {
            unsigned u = (j < 4) ? a[j] : b[j - 4];
            unsigned bits = hi16 ? (u & 0xffff0000u) : (u << 16);
            acc[j] += wgt * __uint_as_float(bits);
        }
    }
    float inv = 1.0f / lt;
    size_t o = (size_t)head * SEQ * DK + (size_t)(w * 32 + row) * DK + d0;
#pragma unroll
    for (int j = 0; j < 8; ++j) out[o + j] = acc[j] * inv;
}

// ---------------------------------------------------------------------------
extern "C" void kernel_launch(void* const* d_in, const int* in_sizes, int n_in,
                              void* d_out, int out_size, void* d_ws, size_t ws_size,
                              hipStream_t stream) {
    const float* x = (const float*)d_in[0];
    const float* qp = (const float*)d_in[1];
    const float* kp = (const float*)d_in[2];
    const float* vp = (const float*)d_in[3];
    float* out = (float*)d_out;

    const size_t WT_SZ = (size_t)NH * DK * E * 2;     // 1,179,648 B
    const size_t QKV_SZ = (size_t)NH * SEQ * DK * 2;  // 6,291,456 B
    const size_t X_SZ = (size_t)SEQ * E * 2;          // 6,291,456 B
    char* ws = (char*)d_ws;
    // Layout: [wt*5][xh][xl] first (dead after proj) -> reused for partials.
    __bf16* wtq_h = (__bf16*)(ws + 0 * WT_SZ);
    __bf16* wtq_l = (__bf16*)(ws + 1 * WT_SZ);
    __bf16* wtk_h = (__bf16*)(ws + 2 * WT_SZ);
    __bf16* wtk_l = (__bf16*)(ws + 3 * WT_SZ);
    __bf16* wtv_h = (__bf16*)(ws + 4 * WT_SZ);
    char* px = ws + 5 * WT_SZ;
    __bf16* xh = (__bf16*)(px + 0 * X_SZ);
    __bf16* xl = (__bf16*)(px + 1 * X_SZ);
    char* p2 = px + 2 * X_SZ;  // 18,481,152
    __bf16* qh = (__bf16*)(p2 + 0 * QKV_SZ);
    __bf16* ql = (__bf16*)(p2 + 1 * QKV_SZ);
    __bf16* kh = (__bf16*)(p2 + 2 * QKV_SZ);
    __bf16* kl = (__bf16*)(p2 + 3 * QKV_SZ);
    __bf16* vt = (__bf16*)(p2 + 4 * QKV_SZ);
    // Partials (3840 x 4352 = 16,711,680 B) reuse [ws, ws+18,481,152).
    char* part = ws;

    hipLaunchKernelGGL(xsplit_kernel, dim3(SEQ * E / 4 / 256), dim3(256), 0, stream,
                       x, xh, xl);
    hipLaunchKernelGGL(wsplit_kernel, dim3((NH * E * DK + 255) / 256), dim3(256), 0, stream,
                       qp, kp, vp, wtq_h, wtq_l, wtk_h, wtk_l, wtv_h);
    hipLaunchKernelGGL(proj_qk_kernel, dim3(768), dim3(256), 0, stream,
                       xh, xl, wtq_h, wtq_l, wtk_h, wtk_l, qh, ql, kh, kl);
    hipLaunchKernelGGL(proj_v_kernel, dim3(768), dim3(256), 0, stream,
                       xh, wtv_h, vt);
    hipLaunchKernelGGL(attn_part_kernel, dim3(960), dim3(256), 0, stream,
                       qh, ql, kh, kl, vt, part);
    hipLaunchKernelGGL(attn_comb_kernel, dim3(1536), dim3(256), 0, stream,
                       part, out);
}